// Round 5
// baseline (966.181 us; speedup 1.0000x reference)
//
#include <hip/hip_runtime.h>
#include <cstdint>

// WeatherSTGNN persistent kernel, round 10: gate-pressure split + direct-global x.
// Round 9 accounting: per-SIMD issue ~87% saturated (MFMA 29% + VALU 57%);
// VGPR_Count pinned at 128 while named persistents ~160 -> part of the acc set
// lives in AGPRs and cell-math/pack VALU pays accvgpr copies. Changes:
//  1. LSTM split {gI,gG}->term=sigm(i)*tanh(g); {gF}->c; {gO}->h. Peak acc
//     32 regs (was 48), 3 MFMA bursts interleaved with VALU. +1 rcp/elem.
//  2. xB built directly from global (no sXb LDS staging): lane(n5,hf) loads
//     feats hf*8..+7 of node n5 one step ahead (8/3 predicated dwords), packs
//     via pk2+selects. Removes index math + 6 ds_write + ds_read per step.
//  3. Everything else unchanged from round 9 (register chain, cpack8 exchange,
//     controlled hoists, bias-slot-11 encoder fold, fused-rcp activations,
//     zero barriers in the 96-step loop).

#define NT 512
#define TSTEPS 48
#define FUT 48

typedef __bf16 bf16;
typedef __attribute__((ext_vector_type(2))) __bf16 bf16x2;
typedef __attribute__((ext_vector_type(8))) __bf16 bf16x8;
typedef __attribute__((ext_vector_type(16))) float f32x16;
typedef unsigned int uint32x4v __attribute__((ext_vector_type(4)));

#define L2E  1.442695041f
#define L2E2 2.885390082f

__device__ __forceinline__ uint32_t pk2(float x, float y) {
  union { bf16x2 h; uint32_t u; } t;
  t.h[0] = (bf16)x; t.h[1] = (bf16)y;
  return t.u;
}

// C-regs v0..v7 (quads q,q+1 of a 32x32 C tile) -> one bf16x8 A/B-frag chunk.
// frag lanes<32 <- quad q, lanes>=32 <- quad q+1; elems 0-3 from hf=0 source
// half, 4-7 from hf=1. permlane32_swap(a,b): r[0]={a.lo,b.lo}, r[1]={a.hi,b.hi}.
__device__ __forceinline__ bf16x8 cpack8(float v0, float v1, float v2, float v3,
                                         float v4, float v5, float v6, float v7) {
  uint32_t a0 = pk2(v0, v1), a1 = pk2(v2, v3);
  uint32_t b0 = pk2(v4, v5), b1 = pk2(v6, v7);
  auto r0 = __builtin_amdgcn_permlane32_swap(a0, b0, false, false);
  auto r1 = __builtin_amdgcn_permlane32_swap(a1, b1, false, false);
  union { uint32x4v u; bf16x8 h; } o;
  o.u = uint32x4v{(uint32_t)r0[0], (uint32_t)r1[0], (uint32_t)r0[1], (uint32_t)r1[1]};
  return o.h;
}

__global__ __launch_bounds__(NT, 2)
void stgnn_kernel(const float* __restrict__ xh, const float* __restrict__ adj,
                  const float* __restrict__ Wenc, const float* __restrict__ benc,
                  const float* __restrict__ Wg1, const float* __restrict__ bg1,
                  const float* __restrict__ Wg2, const float* __restrict__ bg2,
                  const float* __restrict__ Wih, const float* __restrict__ Whh,
                  const float* __restrict__ bih, const float* __restrict__ bhh,
                  const float* __restrict__ Wd1, const float* __restrict__ bd1,
                  const float* __restrict__ Wd2, const float* __restrict__ bd2,
                  float* __restrict__ out) {
  __shared__ __align__(16) bf16 wcatTA[32768];  // Wcat^T A-frag (8 mt x 8 c)
  __shared__ __align__(16) bf16 wg1B[4096];     // Wg1 B-frag (staging -> regs)
  __shared__ __align__(16) bf16 wg2B[4096];     // Wg2 B-frag (staging -> regs)
  __shared__ __align__(16) bf16 wencTA[1024];   // Wenc^T A-frag, row11=benc
  __shared__ __align__(16) bf16 wd1TA[2048];    // Wd1^T A-frag (1 mt x 4 c)
  __shared__ __align__(16) bf16 wd2TA[1024];    // Wd2^T A-frag (1 mt x 2 c, d padded)
  __shared__ __align__(16) bf16 ahHiB[1024];    // Ahat^T hi B-frag (staging -> regs)
  __shared__ __align__(16) bf16 ahLoB[1024];    // Ahat^T lo B-frag (staging -> regs)
  __shared__ __align__(16) float sBg1[64];
  __shared__ __align__(16) float sBg2[64];
  __shared__ __align__(16) float sBih[256];
  __shared__ __align__(16) float sBd1[32];
  __shared__ __align__(16) float sBd2[8];
  __shared__ float sDeg[32];
  __shared__ __align__(16) float sAh[1024];     // normalized Ahat (setup only)

  const int tid = threadIdx.x;
  const int L   = tid & 63;
  const int w   = tid >> 6;
  const int n5  = L & 31;
  const int hf  = L >> 5;
  const long long b = (long long)blockIdx.x * 8 + w;

  // ---------------- static staging ----------------
  for (int i = tid; i < 1024; i += NT) {
    int f = i >> 6, h = i & 63;
    float v = (f < 11) ? Wenc[f * 64 + h] : (f == 11 ? benc[h] : 0.0f);
    wencTA[(h >> 5) * 512 + ((h & 31) + 32 * ((f >> 3) & 1)) * 8 + (f & 7)] = (bf16)v;
  }
  for (int i = tid; i < 4096; i += NT) {
    int k = i >> 6, n = i & 63;
    int off = (((n >> 5) * 4 + (k >> 4)) * 64 + (n & 31) + 32 * ((k >> 3) & 1)) * 8 + (k & 7);
    wg1B[off] = (bf16)Wg1[i];
    wg2B[off] = (bf16)Wg2[i];
  }
  for (int i = tid; i < 32768; i += NT) {
    int gc = i >> 7, k = i & 127;
    float v = (k < 64) ? Wih[gc * 64 + k] : Whh[gc * 64 + (k - 64)];
    wcatTA[((gc >> 5) * 8 + (k >> 4)) * 512 + ((gc & 31) + 32 * ((k >> 3) & 1)) * 8 + (k & 7)] = (bf16)v;
  }
  for (int i = tid; i < 2048; i += NT) {
    int k = i >> 5, n = i & 31;
    wd1TA[(k >> 4) * 512 + (n + 32 * ((k >> 3) & 1)) * 8 + (k & 7)] = (bf16)Wd1[k * 32 + n];
  }
  for (int i = tid; i < 1024; i += NT) {
    int k = i >> 5, d = i & 31;
    float v = (d < 6) ? Wd2[k * 6 + d] : 0.0f;
    wd2TA[(k >> 4) * 512 + (d + 32 * ((k >> 3) & 1)) * 8 + (k & 7)] = (bf16)v;
  }
  for (int i = tid; i < 64; i += NT) { sBg1[i] = bg1[i]; sBg2[i] = bg2[i]; }
  for (int i = tid; i < 256; i += NT) sBih[i] = bih[i] + bhh[i];
  for (int i = tid; i < 32; i += NT) sBd1[i] = bd1[i];
  if (tid < 8) sBd2[tid] = (tid < 6) ? bd2[tid] : 0.0f;
  if (tid < 32) {
    float s = 0.0f;
    for (int j = 0; j < 32; ++j) s += (j == tid) ? 1.0f : adj[tid * 32 + j];
    sDeg[tid] = 1.0f / sqrtf(fmaxf(s, 1.0f));
  }
  __syncthreads();
  for (int i = tid; i < 1024; i += NT) {
    int ii = i >> 5, jj = i & 31;
    float v = (ii == jj) ? 1.0f : adj[i];
    sAh[i] = sDeg[ii] * v * sDeg[jj];
  }
  __syncthreads();
  if (w == 0) {
    #pragma unroll
    for (int c = 0; c < 2; ++c)
      #pragma unroll
      for (int j = 0; j < 8; ++j) {
        int k = 16 * c + 8 * hf + j;
        float v = sAh[n5 * 32 + k];
        bf16 hi = (bf16)v;
        ahHiB[c * 512 + L * 8 + j] = hi;
        ahLoB[c * 512 + L * 8 + j] = (bf16)(v - (float)hi);
      }
  }
  __syncthreads();  // last barrier: everything per-wave / read-only after this

  // controlled hoists (named pre-loop loads survive the per-step clobber)
  const bf16x8 aH0 = *reinterpret_cast<const bf16x8*>(&ahHiB[L * 8]);
  const bf16x8 aL0 = *reinterpret_cast<const bf16x8*>(&ahLoB[L * 8]);
  const bf16x8 aH1 = *reinterpret_cast<const bf16x8*>(&ahHiB[512 + L * 8]);
  const bf16x8 aL1 = *reinterpret_cast<const bf16x8*>(&ahLoB[512 + L * 8]);
  const bf16x8 wencR0 = *reinterpret_cast<const bf16x8*>(&wencTA[L * 8]);
  const bf16x8 wencR1 = *reinterpret_cast<const bf16x8*>(&wencTA[512 + L * 8]);
  bf16x8 wg1R[8], wg2R[8];
  #pragma unroll
  for (int c = 0; c < 8; ++c) {
    wg1R[c] = *reinterpret_cast<const bf16x8*>(&wg1B[c * 512 + L * 8]);
    wg2R[c] = *reinterpret_cast<const bf16x8*>(&wg2B[c * 512 + L * 8]);
  }

  // persistent per-wave registers
  float cx[32];
  #pragma unroll
  for (int i = 0; i < 32; ++i) cx[i] = 0.0f;
  bf16x8 xfhB[8];
  #pragma unroll
  for (int t = 0; t < 8; ++t)
    #pragma unroll
    for (int j = 0; j < 8; ++j) xfhB[t][j] = (bf16)0.0f;
  float predr[4] = {0.f, 0.f, 0.f, 0.f};
  float st0 = 0.f, st1 = 0.f, st2 = 0.f;

  // direct-global x prefetch: lane(n5,hf) owns feats hf*8..+7 of node n5
  float fx0, fx1, fx2, fx3, fx4, fx5, fx6, fx7;
  auto LOADX = [&](int s) {
    const float* px = xh + b * (TSTEPS * 352LL) + (long long)s * 352 + n5 * 11 + (hf << 3);
    fx0 = px[0]; fx1 = px[1]; fx2 = px[2];
    fx3 = fx4 = fx5 = fx6 = fx7 = 0.0f;
    if (!hf) { fx3 = px[3]; fx4 = px[4]; fx5 = px[5]; fx6 = px[6]; fx7 = px[7]; }
  };
  auto PACKX = [&]() -> bf16x8 {
    uint32_t d0 = pk2(fx0, fx1);
    uint32_t d1 = hf ? pk2(fx2, 1.0f) : pk2(fx2, fx3);  // slot11 = 1.0 bias
    uint32_t d2 = hf ? 0u : pk2(fx4, fx5);
    uint32_t d3 = hf ? 0u : pk2(fx6, fx7);
    union { uint32x4v u; bf16x8 h; } xo;
    xo.u = uint32x4v{d0, d1, d2, d3};
    return xo.h;
  };
  LOADX(0);
  bf16x8 xBcur = PACKX();
  LOADX(1);

  #pragma unroll 1
  for (int step = 0; step < TSTEPS + FUT; ++step) {
    // Anti-LICM fence (round-6 lesson: blanket hoist -> scratch spill).
    asm volatile("" ::: "memory");
    const bool de = (step >= TSTEPS);
    const bf16x8 xB = xBcur;  // packed one step ago -> no latency here
    if (!de) {
      if (step + 1 < TSTEPS) xBcur = PACKX();   // fregs hold step+1 data
      if (step + 2 < TSTEPS) LOADX(step + 2);   // prefetch next
    }
    // ---- enc^T = relu(Wenc^T @ x^T), bias via x slot 11 = 1.0 ----
    bf16x8 rA[4];
    #pragma unroll
    for (int mt = 0; mt < 2; ++mt) {
      f32x16 c;
      #pragma unroll
      for (int i = 0; i < 16; ++i) c[i] = 0.0f;
      c = __builtin_amdgcn_mfma_f32_32x32x16_bf16(mt ? wencR1 : wencR0, xB, c, 0, 0, 0);
      rA[2*mt]   = cpack8(fmaxf(c[0], 0.f), fmaxf(c[1], 0.f), fmaxf(c[2], 0.f), fmaxf(c[3], 0.f),
                          fmaxf(c[4], 0.f), fmaxf(c[5], 0.f), fmaxf(c[6], 0.f), fmaxf(c[7], 0.f));
      rA[2*mt+1] = cpack8(fmaxf(c[8], 0.f), fmaxf(c[9], 0.f), fmaxf(c[10], 0.f), fmaxf(c[11], 0.f),
                          fmaxf(c[12], 0.f), fmaxf(c[13], 0.f), fmaxf(c[14], 0.f), fmaxf(c[15], 0.f));
    }
    // ---- t1 = enc @ Wg1 (weights in regs) ----
    bf16x8 nA[4];
    #pragma unroll
    for (int nt = 0; nt < 2; ++nt) {
      f32x16 c;
      #pragma unroll
      for (int i = 0; i < 16; ++i) c[i] = 0.0f;
      #pragma unroll
      for (int cc = 0; cc < 4; ++cc)
        c = __builtin_amdgcn_mfma_f32_32x32x16_bf16(rA[cc], wg1R[nt * 4 + cc], c, 0, 0, 0);
      nA[2*nt]   = cpack8(c[0], c[1], c[2], c[3], c[4], c[5], c[6], c[7]);
      nA[2*nt+1] = cpack8(c[8], c[9], c[10], c[11], c[12], c[13], c[14], c[15]);
    }
    // ---- s1^T = relu(t1^T @ Ahat^T + bg1) ----
    #pragma unroll
    for (int mt = 0; mt < 2; ++mt) {
      f32x16 c;
      #pragma unroll
      for (int g = 0; g < 4; ++g) {
        float4 bb = *reinterpret_cast<const float4*>(&sBg1[32 * mt + 8 * g + 4 * hf]);
        c[4*g+0] = bb.x; c[4*g+1] = bb.y; c[4*g+2] = bb.z; c[4*g+3] = bb.w;
      }
      c = __builtin_amdgcn_mfma_f32_32x32x16_bf16(nA[mt * 2 + 0], aH0, c, 0, 0, 0);
      c = __builtin_amdgcn_mfma_f32_32x32x16_bf16(nA[mt * 2 + 0], aL0, c, 0, 0, 0);
      c = __builtin_amdgcn_mfma_f32_32x32x16_bf16(nA[mt * 2 + 1], aH1, c, 0, 0, 0);
      c = __builtin_amdgcn_mfma_f32_32x32x16_bf16(nA[mt * 2 + 1], aL1, c, 0, 0, 0);
      rA[2*mt]   = cpack8(fmaxf(c[0], 0.f), fmaxf(c[1], 0.f), fmaxf(c[2], 0.f), fmaxf(c[3], 0.f),
                          fmaxf(c[4], 0.f), fmaxf(c[5], 0.f), fmaxf(c[6], 0.f), fmaxf(c[7], 0.f));
      rA[2*mt+1] = cpack8(fmaxf(c[8], 0.f), fmaxf(c[9], 0.f), fmaxf(c[10], 0.f), fmaxf(c[11], 0.f),
                          fmaxf(c[12], 0.f), fmaxf(c[13], 0.f), fmaxf(c[14], 0.f), fmaxf(c[15], 0.f));
    }
    // ---- t2 = s1 @ Wg2 (weights in regs) ----
    #pragma unroll
    for (int nt = 0; nt < 2; ++nt) {
      f32x16 c;
      #pragma unroll
      for (int i = 0; i < 16; ++i) c[i] = 0.0f;
      #pragma unroll
      for (int cc = 0; cc < 4; ++cc)
        c = __builtin_amdgcn_mfma_f32_32x32x16_bf16(rA[cc], wg2R[nt * 4 + cc], c, 0, 0, 0);
      nA[2*nt]   = cpack8(c[0], c[1], c[2], c[3], c[4], c[5], c[6], c[7]);
      nA[2*nt+1] = cpack8(c[8], c[9], c[10], c[11], c[12], c[13], c[14], c[15]);
    }
    // ---- xf^T = relu(t2^T @ Ahat^T + bg2) -> xfhB[0..3] ----
    #pragma unroll
    for (int mt = 0; mt < 2; ++mt) {
      f32x16 c;
      #pragma unroll
      for (int g = 0; g < 4; ++g) {
        float4 bb = *reinterpret_cast<const float4*>(&sBg2[32 * mt + 8 * g + 4 * hf]);
        c[4*g+0] = bb.x; c[4*g+1] = bb.y; c[4*g+2] = bb.z; c[4*g+3] = bb.w;
      }
      c = __builtin_amdgcn_mfma_f32_32x32x16_bf16(nA[mt * 2 + 0], aH0, c, 0, 0, 0);
      c = __builtin_amdgcn_mfma_f32_32x32x16_bf16(nA[mt * 2 + 0], aL0, c, 0, 0, 0);
      c = __builtin_amdgcn_mfma_f32_32x32x16_bf16(nA[mt * 2 + 1], aH1, c, 0, 0, 0);
      c = __builtin_amdgcn_mfma_f32_32x32x16_bf16(nA[mt * 2 + 1], aL1, c, 0, 0, 0);
      xfhB[2*mt]   = cpack8(fmaxf(c[0], 0.f), fmaxf(c[1], 0.f), fmaxf(c[2], 0.f), fmaxf(c[3], 0.f),
                            fmaxf(c[4], 0.f), fmaxf(c[5], 0.f), fmaxf(c[6], 0.f), fmaxf(c[7], 0.f));
      xfhB[2*mt+1] = cpack8(fmaxf(c[8], 0.f), fmaxf(c[9], 0.f), fmaxf(c[10], 0.f), fmaxf(c[11], 0.f),
                            fmaxf(c[12], 0.f), fmaxf(c[13], 0.f), fmaxf(c[14], 0.f), fmaxf(c[15], 0.f));
    }
    // ---- LSTM, 3-burst split: {gI,gG}->term, {gF}->c, {gO}->h ----
    bf16x8 hN[4];
    #pragma unroll
    for (int p = 0; p < 2; ++p) {
      f32x16 gI, gG;
      #pragma unroll
      for (int g = 0; g < 4; ++g) {
        float4 bI = *reinterpret_cast<const float4*>(&sBih[      32 * p + 8 * g + 4 * hf]);
        float4 bG = *reinterpret_cast<const float4*>(&sBih[128 + 32 * p + 8 * g + 4 * hf]);
        gI[4*g+0]=bI.x; gI[4*g+1]=bI.y; gI[4*g+2]=bI.z; gI[4*g+3]=bI.w;
        gG[4*g+0]=bG.x; gG[4*g+1]=bG.y; gG[4*g+2]=bG.z; gG[4*g+3]=bG.w;
      }
      #pragma unroll
      for (int cc = 0; cc < 8; ++cc) {
        gI = __builtin_amdgcn_mfma_f32_32x32x16_bf16(
               *reinterpret_cast<const bf16x8*>(&wcatTA[((0 + p) * 8 + cc) * 512 + L * 8]),
               xfhB[cc], gI, 0, 0, 0);
        gG = __builtin_amdgcn_mfma_f32_32x32x16_bf16(
               *reinterpret_cast<const bf16x8*>(&wcatTA[((4 + p) * 8 + cc) * 512 + L * 8]),
               xfhB[cc], gG, 0, 0, 0);
      }
      float term[16];
      #pragma unroll
      for (int ri = 0; ri < 16; ++ri) {
        float ei = __builtin_amdgcn_exp2f(gI[ri] * -L2E);
        float eg = __builtin_amdgcn_exp2f(gG[ri] * L2E2);
        float A  = 1.0f + ei;
        float T  = __builtin_fmaf(A, eg, A);              // (1+ei)(eg+1)
        term[ri] = (eg - 1.0f) * __builtin_amdgcn_rcpf(T);  // sigm(i)*tanh(g)
      }
      f32x16 gF;
      #pragma unroll
      for (int g = 0; g < 4; ++g) {
        float4 bF = *reinterpret_cast<const float4*>(&sBih[64 + 32 * p + 8 * g + 4 * hf]);
        gF[4*g+0]=bF.x; gF[4*g+1]=bF.y; gF[4*g+2]=bF.z; gF[4*g+3]=bF.w;
      }
      #pragma unroll
      for (int cc = 0; cc < 8; ++cc)
        gF = __builtin_amdgcn_mfma_f32_32x32x16_bf16(
               *reinterpret_cast<const bf16x8*>(&wcatTA[((2 + p) * 8 + cc) * 512 + L * 8]),
               xfhB[cc], gF, 0, 0, 0);
      #pragma unroll
      for (int ri = 0; ri < 16; ++ri) {
        float ef = __builtin_amdgcn_exp2f(gF[ri] * -L2E);
        cx[p * 16 + ri] = __builtin_fmaf(cx[p * 16 + ri],
                            __builtin_amdgcn_rcpf(1.0f + ef), term[ri]);
      }
      f32x16 gO;
      #pragma unroll
      for (int g = 0; g < 4; ++g) {
        float4 bO = *reinterpret_cast<const float4*>(&sBih[192 + 32 * p + 8 * g + 4 * hf]);
        gO[4*g+0]=bO.x; gO[4*g+1]=bO.y; gO[4*g+2]=bO.z; gO[4*g+3]=bO.w;
      }
      #pragma unroll
      for (int cc = 0; cc < 8; ++cc)
        gO = __builtin_amdgcn_mfma_f32_32x32x16_bf16(
               *reinterpret_cast<const bf16x8*>(&wcatTA[((6 + p) * 8 + cc) * 512 + L * 8]),
               xfhB[cc], gO, 0, 0, 0);
      float hq[16];
      #pragma unroll
      for (int ri = 0; ri < 16; ++ri) {
        float eo = __builtin_amdgcn_exp2f(gO[ri] * -L2E);
        float ec = __builtin_amdgcn_exp2f(cx[p * 16 + ri] * L2E2);
        float B1 = 1.0f + eo;
        float T2 = __builtin_fmaf(B1, ec, B1);            // (1+eo)(ec+1)
        hq[ri] = (ec - 1.0f) * __builtin_amdgcn_rcpf(T2);
      }
      hN[2*p]   = cpack8(hq[0], hq[1], hq[2], hq[3], hq[4], hq[5], hq[6], hq[7]);
      hN[2*p+1] = cpack8(hq[8], hq[9], hq[10], hq[11], hq[12], hq[13], hq[14], hq[15]);
    }
    #pragma unroll
    for (int t = 0; t < 4; ++t) xfhB[4 + t] = hN[t];
    // ---- decoder: d1^T, d2^T, pred update, next-xB build (all in regs) ----
    if (de) {
      if (step == TSTEPS) {
        const float* px = xh + ((b * TSTEPS + (TSTEPS - 1)) * 32 + n5) * 11;
        if (hf == 0) { predr[0] = px[0]; predr[1] = px[1]; predr[2] = px[2]; predr[3] = px[3]; }
        else         { predr[0] = px[4]; predr[1] = px[5]; }
        st0 = px[6 + 2 * hf]; st1 = px[7 + 2 * hf]; st2 = px[10];
      }
      f32x16 cD;
      #pragma unroll
      for (int g = 0; g < 4; ++g) {
        float4 bb = *reinterpret_cast<const float4*>(&sBd1[8 * g + 4 * hf]);
        cD[4*g+0] = bb.x; cD[4*g+1] = bb.y; cD[4*g+2] = bb.z; cD[4*g+3] = bb.w;
      }
      #pragma unroll
      for (int cc = 0; cc < 4; ++cc)
        cD = __builtin_amdgcn_mfma_f32_32x32x16_bf16(
               *reinterpret_cast<const bf16x8*>(&wd1TA[cc * 512 + L * 8]), xfhB[4 + cc], cD, 0, 0, 0);
      bf16x8 rB0 = cpack8(fmaxf(cD[0], 0.f), fmaxf(cD[1], 0.f), fmaxf(cD[2], 0.f), fmaxf(cD[3], 0.f),
                          fmaxf(cD[4], 0.f), fmaxf(cD[5], 0.f), fmaxf(cD[6], 0.f), fmaxf(cD[7], 0.f));
      bf16x8 rB1 = cpack8(fmaxf(cD[8], 0.f), fmaxf(cD[9], 0.f), fmaxf(cD[10], 0.f), fmaxf(cD[11], 0.f),
                          fmaxf(cD[12], 0.f), fmaxf(cD[13], 0.f), fmaxf(cD[14], 0.f), fmaxf(cD[15], 0.f));
      f32x16 c2;
      #pragma unroll
      for (int i = 0; i < 4; ++i) c2[i] = sBd2[4 * hf + i];
      #pragma unroll
      for (int i = 4; i < 16; ++i) c2[i] = 0.0f;
      c2 = __builtin_amdgcn_mfma_f32_32x32x16_bf16(
             *reinterpret_cast<const bf16x8*>(&wd2TA[L * 8]), rB0, c2, 0, 0, 0);
      c2 = __builtin_amdgcn_mfma_f32_32x32x16_bf16(
             *reinterpret_cast<const bf16x8*>(&wd2TA[512 + L * 8]), rB1, c2, 0, 0, 0);
      float* op = out + ((b * FUT + (step - TSTEPS)) * 32 + n5) * 6;
      if (hf == 0) {
        float p0 = predr[0] + c2[0];
        float p1 = predr[1] + c2[1];
        float p2 = predr[2] + c2[2];
        float p3 = predr[3] + c2[3];
        predr[0] = p0; predr[1] = p1; predr[2] = p2; predr[3] = p3;
        *reinterpret_cast<float2*>(op + 0) = make_float2(p0, p1);
        *reinterpret_cast<float2*>(op + 2) = make_float2(p2, p3);
      } else {
        float p4 = predr[0] + c2[0];
        float p5 = predr[1] + c2[1];
        predr[0] = p4; predr[1] = p5;
        *reinterpret_cast<float2*>(op + 4) = make_float2(p4, p5);
      }
      // next xB = [pred(6) | stat(5) | 1.0 bias | 0...] in frag layout.
      uint32_t pa = pk2(predr[0], predr[1]);          // hf0:{p0,p1}  hf1:{p4,p5}
      auto sw = __builtin_amdgcn_permlane32_swap(pa, pa, false, false);
      uint32_t d0 = hf ? pk2(st0, st1)  : pa;
      uint32_t d1 = hf ? pk2(st2, 1.0f) : pk2(predr[2], predr[3]);  // feat11=1.0
      uint32_t d2 = hf ? 0u : (uint32_t)sw[1];        // {p4,p5} pulled from hf1
      uint32_t d3 = hf ? 0u : pk2(st0, st1);
      union { uint32x4v u; bf16x8 h; } xo;
      xo.u = uint32x4v{d0, d1, d2, d3};
      xBcur = xo.h;
    }
  }
}

extern "C" void kernel_launch(void* const* d_in, const int* in_sizes, int n_in,
                              void* d_out, int out_size, void* d_ws, size_t ws_size,
                              hipStream_t stream) {
  (void)in_sizes; (void)n_in; (void)d_ws; (void)ws_size; (void)out_size;
  const float* xh   = (const float*)d_in[0];
  const float* adj  = (const float*)d_in[1];
  const float* Wenc = (const float*)d_in[2];
  const float* benc = (const float*)d_in[3];
  const float* Wg1  = (const float*)d_in[4];
  const float* bg1  = (const float*)d_in[5];
  const float* Wg2  = (const float*)d_in[6];
  const float* bg2  = (const float*)d_in[7];
  const float* Wih  = (const float*)d_in[8];
  const float* Whh  = (const float*)d_in[9];
  const float* bih  = (const float*)d_in[10];
  const float* bhh  = (const float*)d_in[11];
  const float* Wd1  = (const float*)d_in[12];
  const float* bd1  = (const float*)d_in[13];
  const float* Wd2  = (const float*)d_in[14];
  const float* bd2  = (const float*)d_in[15];
  float* out = (float*)d_out;
  stgnn_kernel<<<dim3(256), dim3(NT), 0, stream>>>(
      xh, adj, Wenc, benc, Wg1, bg1, Wg2, bg2,
      Wih, Whh, bih, bhh, Wd1, bd1, Wd2, bd2, out);
}

// Round 6
// 924.115 us; speedup vs baseline: 1.0455x; 1.0455x over previous
//
#include <hip/hip_runtime.h>
#include <cstdint>

// WeatherSTGNN persistent kernel, round 11: cross-step software pipelining.
// Round 10 was neutral -> theory update: counters ambiguous between issue-
// saturation and dependency-stall; bottom-up arithmetic (98 MFMA x 8cyc +
// ~256 trans x 8 + ~500 VALU x 2 ~= 35% of issue capacity) favors STALL-bound:
// each step is one serial chain with only 2 waves/SIMD to hide it, and
// occupancy is locked (regs+LDS both bind at 2 waves/SIMD).
// Fix: the xf-chain of step s+1 (enc->t1->s1->t2->xf, 34 MFMAs) depends only
// on x[s+1], NOT on step s's LSTM. Encoder loop now carries xfhB[0..3] =
// xf(x[s]) one step ahead and interleaves {LSTM gates/cell of s} with
// {xf-chain of s+1} in ONE basic block (loops split encoder/decoder, LOADX
// branchless) so the scheduler can hide both chains' latency. Decoder stays
// serial (pred->x dependency is fundamental). wg1R/wg2R un-hoisted to LDS
// (-64 regs) to fund the pipeline's live set.

#define NT 512
#define TSTEPS 48
#define FUT 48

typedef __bf16 bf16;
typedef __attribute__((ext_vector_type(2))) __bf16 bf16x2;
typedef __attribute__((ext_vector_type(8))) __bf16 bf16x8;
typedef __attribute__((ext_vector_type(16))) float f32x16;
typedef unsigned int uint32x4v __attribute__((ext_vector_type(4)));

#define L2E  1.442695041f
#define L2E2 2.885390082f

__device__ __forceinline__ uint32_t pk2(float x, float y) {
  union { bf16x2 h; uint32_t u; } t;
  t.h[0] = (bf16)x; t.h[1] = (bf16)y;
  return t.u;
}

// C-regs v0..v7 (quads q,q+1 of a 32x32 C tile) -> one bf16x8 A/B-frag chunk.
// frag lanes<32 <- quad q, lanes>=32 <- quad q+1; elems 0-3 from hf=0 source
// half, 4-7 from hf=1. permlane32_swap(a,b): r[0]={a.lo,b.lo}, r[1]={a.hi,b.hi}.
__device__ __forceinline__ bf16x8 cpack8(float v0, float v1, float v2, float v3,
                                         float v4, float v5, float v6, float v7) {
  uint32_t a0 = pk2(v0, v1), a1 = pk2(v2, v3);
  uint32_t b0 = pk2(v4, v5), b1 = pk2(v6, v7);
  auto r0 = __builtin_amdgcn_permlane32_swap(a0, b0, false, false);
  auto r1 = __builtin_amdgcn_permlane32_swap(a1, b1, false, false);
  union { uint32x4v u; bf16x8 h; } o;
  o.u = uint32x4v{(uint32_t)r0[0], (uint32_t)r1[0], (uint32_t)r0[1], (uint32_t)r1[1]};
  return o.h;
}

__global__ __launch_bounds__(NT, 2)
void stgnn_kernel(const float* __restrict__ xh, const float* __restrict__ adj,
                  const float* __restrict__ Wenc, const float* __restrict__ benc,
                  const float* __restrict__ Wg1, const float* __restrict__ bg1,
                  const float* __restrict__ Wg2, const float* __restrict__ bg2,
                  const float* __restrict__ Wih, const float* __restrict__ Whh,
                  const float* __restrict__ bih, const float* __restrict__ bhh,
                  const float* __restrict__ Wd1, const float* __restrict__ bd1,
                  const float* __restrict__ Wd2, const float* __restrict__ bd2,
                  float* __restrict__ out) {
  __shared__ __align__(16) bf16 wcatTA[32768];  // Wcat^T A-frag (8 mt x 8 c)
  __shared__ __align__(16) bf16 wg1B[4096];     // Wg1 B-frag (read in-loop)
  __shared__ __align__(16) bf16 wg2B[4096];     // Wg2 B-frag (read in-loop)
  __shared__ __align__(16) bf16 wencTA[1024];   // Wenc^T A-frag, row11=benc
  __shared__ __align__(16) bf16 wd1TA[2048];    // Wd1^T A-frag (1 mt x 4 c)
  __shared__ __align__(16) bf16 wd2TA[1024];    // Wd2^T A-frag (1 mt x 2 c, d padded)
  __shared__ __align__(16) bf16 ahHiB[1024];    // Ahat^T hi B-frag (staging -> regs)
  __shared__ __align__(16) bf16 ahLoB[1024];    // Ahat^T lo B-frag (staging -> regs)
  __shared__ __align__(16) float sBg1[64];
  __shared__ __align__(16) float sBg2[64];
  __shared__ __align__(16) float sBih[256];
  __shared__ __align__(16) float sBd1[32];
  __shared__ __align__(16) float sBd2[8];
  __shared__ float sDeg[32];
  __shared__ __align__(16) float sAh[1024];     // normalized Ahat (setup only)

  const int tid = threadIdx.x;
  const int L   = tid & 63;
  const int w   = tid >> 6;
  const int n5  = L & 31;
  const int hf  = L >> 5;
  const long long b = (long long)blockIdx.x * 8 + w;

  // ---------------- static staging ----------------
  for (int i = tid; i < 1024; i += NT) {
    int f = i >> 6, h = i & 63;
    float v = (f < 11) ? Wenc[f * 64 + h] : (f == 11 ? benc[h] : 0.0f);
    wencTA[(h >> 5) * 512 + ((h & 31) + 32 * ((f >> 3) & 1)) * 8 + (f & 7)] = (bf16)v;
  }
  for (int i = tid; i < 4096; i += NT) {
    int k = i >> 6, n = i & 63;
    int off = (((n >> 5) * 4 + (k >> 4)) * 64 + (n & 31) + 32 * ((k >> 3) & 1)) * 8 + (k & 7);
    wg1B[off] = (bf16)Wg1[i];
    wg2B[off] = (bf16)Wg2[i];
  }
  for (int i = tid; i < 32768; i += NT) {
    int gc = i >> 7, k = i & 127;
    float v = (k < 64) ? Wih[gc * 64 + k] : Whh[gc * 64 + (k - 64)];
    wcatTA[((gc >> 5) * 8 + (k >> 4)) * 512 + ((gc & 31) + 32 * ((k >> 3) & 1)) * 8 + (k & 7)] = (bf16)v;
  }
  for (int i = tid; i < 2048; i += NT) {
    int k = i >> 5, n = i & 31;
    wd1TA[(k >> 4) * 512 + (n + 32 * ((k >> 3) & 1)) * 8 + (k & 7)] = (bf16)Wd1[k * 32 + n];
  }
  for (int i = tid; i < 1024; i += NT) {
    int k = i >> 5, d = i & 31;
    float v = (d < 6) ? Wd2[k * 6 + d] : 0.0f;
    wd2TA[(k >> 4) * 512 + (d + 32 * ((k >> 3) & 1)) * 8 + (k & 7)] = (bf16)v;
  }
  for (int i = tid; i < 64; i += NT) { sBg1[i] = bg1[i]; sBg2[i] = bg2[i]; }
  for (int i = tid; i < 256; i += NT) sBih[i] = bih[i] + bhh[i];
  for (int i = tid; i < 32; i += NT) sBd1[i] = bd1[i];
  if (tid < 8) sBd2[tid] = (tid < 6) ? bd2[tid] : 0.0f;
  if (tid < 32) {
    float s = 0.0f;
    for (int j = 0; j < 32; ++j) s += (j == tid) ? 1.0f : adj[tid * 32 + j];
    sDeg[tid] = 1.0f / sqrtf(fmaxf(s, 1.0f));
  }
  __syncthreads();
  for (int i = tid; i < 1024; i += NT) {
    int ii = i >> 5, jj = i & 31;
    float v = (ii == jj) ? 1.0f : adj[i];
    sAh[i] = sDeg[ii] * v * sDeg[jj];
  }
  __syncthreads();
  if (w == 0) {
    #pragma unroll
    for (int c = 0; c < 2; ++c)
      #pragma unroll
      for (int j = 0; j < 8; ++j) {
        int k = 16 * c + 8 * hf + j;
        float v = sAh[n5 * 32 + k];
        bf16 hi = (bf16)v;
        ahHiB[c * 512 + L * 8 + j] = hi;
        ahLoB[c * 512 + L * 8 + j] = (bf16)(v - (float)hi);
      }
  }
  __syncthreads();  // last barrier: everything per-wave / read-only after this

  // controlled hoists (Ahat + Wenc only; wg1/wg2 stay in LDS this round)
  const bf16x8 aH0 = *reinterpret_cast<const bf16x8*>(&ahHiB[L * 8]);
  const bf16x8 aL0 = *reinterpret_cast<const bf16x8*>(&ahLoB[L * 8]);
  const bf16x8 aH1 = *reinterpret_cast<const bf16x8*>(&ahHiB[512 + L * 8]);
  const bf16x8 aL1 = *reinterpret_cast<const bf16x8*>(&ahLoB[512 + L * 8]);
  const bf16x8 wencR0 = *reinterpret_cast<const bf16x8*>(&wencTA[L * 8]);
  const bf16x8 wencR1 = *reinterpret_cast<const bf16x8*>(&wencTA[512 + L * 8]);

  // persistent per-wave registers
  float cx[32];
  #pragma unroll
  for (int i = 0; i < 32; ++i) cx[i] = 0.0f;
  bf16x8 xfhB[8];
  #pragma unroll
  for (int t = 0; t < 8; ++t)
    #pragma unroll
    for (int j = 0; j < 8; ++j) xfhB[t][j] = (bf16)0.0f;
  float predr[4] = {0.f, 0.f, 0.f, 0.f};
  float st0 = 0.f, st1 = 0.f, st2 = 0.f;

  // ---- helpers (all inlined; arrays fully reg-promoted after unroll) ----
  auto RELUPK = [&](const f32x16& c, bf16x8& o0, bf16x8& o1) {
    o0 = cpack8(fmaxf(c[0], 0.f), fmaxf(c[1], 0.f), fmaxf(c[2], 0.f), fmaxf(c[3], 0.f),
                fmaxf(c[4], 0.f), fmaxf(c[5], 0.f), fmaxf(c[6], 0.f), fmaxf(c[7], 0.f));
    o1 = cpack8(fmaxf(c[8], 0.f), fmaxf(c[9], 0.f), fmaxf(c[10], 0.f), fmaxf(c[11], 0.f),
                fmaxf(c[12], 0.f), fmaxf(c[13], 0.f), fmaxf(c[14], 0.f), fmaxf(c[15], 0.f));
  };
  auto RAWPK = [&](const f32x16& c, bf16x8& o0, bf16x8& o1) {
    o0 = cpack8(c[0], c[1], c[2], c[3], c[4], c[5], c[6], c[7]);
    o1 = cpack8(c[8], c[9], c[10], c[11], c[12], c[13], c[14], c[15]);
  };
  auto ST_ENC = [&](const bf16x8& xB, bf16x8* rA) {
    #pragma unroll
    for (int mt = 0; mt < 2; ++mt) {
      f32x16 c;
      #pragma unroll
      for (int i = 0; i < 16; ++i) c[i] = 0.0f;
      c = __builtin_amdgcn_mfma_f32_32x32x16_bf16(mt ? wencR1 : wencR0, xB, c, 0, 0, 0);
      RELUPK(c, rA[2*mt], rA[2*mt+1]);
    }
  };
  auto ST_MUL = [&](const bf16* wB, const bf16x8* rA, bf16x8* nA) {  // t1 / t2
    #pragma unroll
    for (int nt = 0; nt < 2; ++nt) {
      f32x16 c;
      #pragma unroll
      for (int i = 0; i < 16; ++i) c[i] = 0.0f;
      #pragma unroll
      for (int cc = 0; cc < 4; ++cc)
        c = __builtin_amdgcn_mfma_f32_32x32x16_bf16(rA[cc],
              *reinterpret_cast<const bf16x8*>(&wB[(nt * 4 + cc) * 512 + L * 8]), c, 0, 0, 0);
      RAWPK(c, nA[2*nt], nA[2*nt+1]);
    }
  };
  auto ST_AH = [&](const float* sBias, const bf16x8* nA, bf16x8* rA) {  // s1 / xf
    #pragma unroll
    for (int mt = 0; mt < 2; ++mt) {
      f32x16 c;
      #pragma unroll
      for (int g = 0; g < 4; ++g) {
        float4 bb = *reinterpret_cast<const float4*>(&sBias[32 * mt + 8 * g + 4 * hf]);
        c[4*g+0] = bb.x; c[4*g+1] = bb.y; c[4*g+2] = bb.z; c[4*g+3] = bb.w;
      }
      c = __builtin_amdgcn_mfma_f32_32x32x16_bf16(nA[mt * 2 + 0], aH0, c, 0, 0, 0);
      c = __builtin_amdgcn_mfma_f32_32x32x16_bf16(nA[mt * 2 + 0], aL0, c, 0, 0, 0);
      c = __builtin_amdgcn_mfma_f32_32x32x16_bf16(nA[mt * 2 + 1], aH1, c, 0, 0, 0);
      c = __builtin_amdgcn_mfma_f32_32x32x16_bf16(nA[mt * 2 + 1], aL1, c, 0, 0, 0);
      RELUPK(c, rA[2*mt], rA[2*mt+1]);
    }
  };
  auto CHAIN = [&](const bf16x8& xB, bf16x8* xfN) {  // full xf-chain
    bf16x8 rA[4], nA[4];
    ST_ENC(xB, rA);
    ST_MUL(wg1B, rA, nA);
    ST_AH(sBg1, nA, rA);
    ST_MUL(wg2B, rA, nA);
    ST_AH(sBg2, nA, xfN);
  };
  auto GATE2 = [&](int p, int gidx0, int gidx1, f32x16& gA, f32x16& gB) {
    #pragma unroll
    for (int g = 0; g < 4; ++g) {
      float4 bA = *reinterpret_cast<const float4*>(&sBih[gidx0 * 64 + 32 * p + 8 * g + 4 * hf]);
      float4 bBv = *reinterpret_cast<const float4*>(&sBih[gidx1 * 64 + 32 * p + 8 * g + 4 * hf]);
      gA[4*g+0]=bA.x; gA[4*g+1]=bA.y; gA[4*g+2]=bA.z; gA[4*g+3]=bA.w;
      gB[4*g+0]=bBv.x; gB[4*g+1]=bBv.y; gB[4*g+2]=bBv.z; gB[4*g+3]=bBv.w;
    }
    #pragma unroll
    for (int cc = 0; cc < 8; ++cc) {
      gA = __builtin_amdgcn_mfma_f32_32x32x16_bf16(
             *reinterpret_cast<const bf16x8*>(&wcatTA[((gidx0 * 2 + p) * 8 + cc) * 512 + L * 8]),
             xfhB[cc], gA, 0, 0, 0);
      gB = __builtin_amdgcn_mfma_f32_32x32x16_bf16(
             *reinterpret_cast<const bf16x8*>(&wcatTA[((gidx1 * 2 + p) * 8 + cc) * 512 + L * 8]),
             xfhB[cc], gB, 0, 0, 0);
    }
  };
  auto GATE1 = [&](int p, int gidx, f32x16& gX) {
    #pragma unroll
    for (int g = 0; g < 4; ++g) {
      float4 bb = *reinterpret_cast<const float4*>(&sBih[gidx * 64 + 32 * p + 8 * g + 4 * hf]);
      gX[4*g+0]=bb.x; gX[4*g+1]=bb.y; gX[4*g+2]=bb.z; gX[4*g+3]=bb.w;
    }
    #pragma unroll
    for (int cc = 0; cc < 8; ++cc)
      gX = __builtin_amdgcn_mfma_f32_32x32x16_bf16(
             *reinterpret_cast<const bf16x8*>(&wcatTA[((gidx * 2 + p) * 8 + cc) * 512 + L * 8]),
             xfhB[cc], gX, 0, 0, 0);
  };
  auto TERM = [&](const f32x16& gI, const f32x16& gG, float* term) {
    #pragma unroll
    for (int ri = 0; ri < 16; ++ri) {
      float ei = __builtin_amdgcn_exp2f(gI[ri] * -L2E);
      float eg = __builtin_amdgcn_exp2f(gG[ri] * L2E2);
      float A  = 1.0f + ei;
      float T  = __builtin_fmaf(A, eg, A);
      term[ri] = (eg - 1.0f) * __builtin_amdgcn_rcpf(T);  // sigm(i)*tanh(g)
    }
  };
  auto CUPD = [&](int p, const f32x16& gF, const float* term) {
    #pragma unroll
    for (int ri = 0; ri < 16; ++ri) {
      float ef = __builtin_amdgcn_exp2f(gF[ri] * -L2E);
      cx[p * 16 + ri] = __builtin_fmaf(cx[p * 16 + ri],
                          __builtin_amdgcn_rcpf(1.0f + ef), term[ri]);
    }
  };
  auto HOUT = [&](int p, const f32x16& gO, bf16x8& h0, bf16x8& h1) {
    float hq[16];
    #pragma unroll
    for (int ri = 0; ri < 16; ++ri) {
      float eo = __builtin_amdgcn_exp2f(gO[ri] * -L2E);
      float ec = __builtin_amdgcn_exp2f(cx[p * 16 + ri] * L2E2);
      float B1 = 1.0f + eo;
      float T2 = __builtin_fmaf(B1, ec, B1);
      hq[ri] = (ec - 1.0f) * __builtin_amdgcn_rcpf(T2);
    }
    h0 = cpack8(hq[0], hq[1], hq[2], hq[3], hq[4], hq[5], hq[6], hq[7]);
    h1 = cpack8(hq[8], hq[9], hq[10], hq[11], hq[12], hq[13], hq[14], hq[15]);
  };

  // direct-global x prefetch (branchless: hf1 lanes re-read own-node data
  // for the unused slots instead of diverging -> single BB)
  float fx0, fx1, fx2, fx3, fx4, fx5, fx6, fx7;
  auto LOADX = [&](int s) {
    const float* px = xh + b * (TSTEPS * 352LL) + (long long)s * 352 + n5 * 11 + (hf << 3);
    const float* q  = hf ? px - 8 : px;   // hf1 tail slots: safe dummy reads
    fx0 = px[0]; fx1 = px[1]; fx2 = px[2];
    fx3 = q[3]; fx4 = q[4]; fx5 = q[5]; fx6 = q[6]; fx7 = q[7];
  };
  auto PACKX = [&]() -> bf16x8 {
    uint32_t d0 = pk2(fx0, fx1);
    uint32_t d1 = hf ? pk2(fx2, 1.0f) : pk2(fx2, fx3);  // slot11 = 1.0 bias
    uint32_t d2 = hf ? 0u : pk2(fx4, fx5);
    uint32_t d3 = hf ? 0u : pk2(fx6, fx7);
    union { uint32x4v u; bf16x8 h; } xo;
    xo.u = uint32x4v{d0, d1, d2, d3};
    return xo.h;
  };
  auto BUILD_DECX = [&]() -> bf16x8 {
    uint32_t pa = pk2(predr[0], predr[1]);          // hf0:{p0,p1}  hf1:{p4,p5}
    auto sw = __builtin_amdgcn_permlane32_swap(pa, pa, false, false);
    uint32_t d0 = hf ? pk2(st0, st1)  : pa;
    uint32_t d1 = hf ? pk2(st2, 1.0f) : pk2(predr[2], predr[3]);
    uint32_t d2 = hf ? 0u : (uint32_t)sw[1];        // {p4,p5} pulled from hf1
    uint32_t d3 = hf ? 0u : pk2(st0, st1);
    union { uint32x4v u; bf16x8 h; } xo;
    xo.u = uint32x4v{d0, d1, d2, d3};
    return xo.h;
  };

  // ---------------- prologue: xf(x[0]) ahead of the loop ----------------
  LOADX(0);
  {
    bf16x8 xB0 = PACKX();
    bf16x8 xfN[4];
    CHAIN(xB0, xfN);
    #pragma unroll
    for (int t = 0; t < 4; ++t) xfhB[t] = xfN[t];
  }
  LOADX(1);
  bf16x8 xBcur = PACKX();   // x[1]
  LOADX(2);                 // fx <- x[2]

  // ---------------- encoder: LSTM(s) interleaved with xf-chain(s+1) -------
  #pragma unroll 1
  for (int s = 0; s < TSTEPS; ++s) {
    asm volatile("" ::: "memory");  // anti-LICM fence (round-6 lesson)
    // p0 gate I/G MFMAs issue first; chain segments slot between gate bursts
    f32x16 gI0, gG0;
    GATE2(0, 0, 2, gI0, gG0);
    bf16x8 rA[4], nA[4], xfN[4];
    ST_ENC(xBcur, rA);                // chain A (independent of LSTM)
    ST_MUL(wg1B, rA, nA);
    f32x16 gF0;
    GATE1(0, 1, gF0);
    float term0[16];
    TERM(gI0, gG0, term0);
    ST_AH(sBg1, nA, rA);              // chain B
    ST_MUL(wg2B, rA, nA);
    f32x16 gO0;
    GATE1(0, 3, gO0);
    CUPD(0, gF0, term0);
    bf16x8 hN[4];
    HOUT(0, gO0, hN[0], hN[1]);
    ST_AH(sBg2, nA, xfN);             // chain C -> xf(x[s+1])
    f32x16 gI1, gG1;
    GATE2(1, 0, 2, gI1, gG1);
    f32x16 gF1;
    GATE1(1, 1, gF1);
    float term1[16];
    TERM(gI1, gG1, term1);
    f32x16 gO1;
    GATE1(1, 3, gO1);
    CUPD(1, gF1, term1);
    HOUT(1, gO1, hN[2], hN[3]);
    // commit AFTER all gate MFMAs consumed the old xfhB
    #pragma unroll
    for (int t = 0; t < 4; ++t) { xfhB[t] = xfN[t]; xfhB[4 + t] = hN[t]; }
    xBcur = PACKX();                                  // x[s+2]
    int nsl = (s + 3 < TSTEPS) ? s + 3 : TSTEPS - 1;  // clamped prefetch
    LOADX(nsl);
  }

  // ---------------- decoder peel: pred/stat init, first x ----------------
  {
    const float* px = xh + ((b * TSTEPS + (TSTEPS - 1)) * 32 + n5) * 11;
    if (hf == 0) { predr[0] = px[0]; predr[1] = px[1]; predr[2] = px[2]; predr[3] = px[3]; }
    else         { predr[0] = px[4]; predr[1] = px[5]; }
    st0 = px[6 + 2 * hf]; st1 = px[7 + 2 * hf]; st2 = px[10];
    xBcur = BUILD_DECX();
  }

  // ---------------- decoder: serial chain (pred -> x dependency) ----------
  #pragma unroll 1
  for (int s = 0; s < FUT; ++s) {
    asm volatile("" ::: "memory");
    bf16x8 xfN[4];
    CHAIN(xBcur, xfN);
    #pragma unroll
    for (int t = 0; t < 4; ++t) xfhB[t] = xfN[t];
    bf16x8 hN[4];
    #pragma unroll
    for (int p = 0; p < 2; ++p) {
      f32x16 gI, gG;
      GATE2(p, 0, 2, gI, gG);
      float term[16];
      TERM(gI, gG, term);
      f32x16 gF;
      GATE1(p, 1, gF);
      CUPD(p, gF, term);
      f32x16 gO;
      GATE1(p, 3, gO);
      HOUT(p, gO, hN[2*p], hN[2*p+1]);
    }
    #pragma unroll
    for (int t = 0; t < 4; ++t) xfhB[4 + t] = hN[t];
    // d1^T / d2^T / pred update / store
    f32x16 cD;
    #pragma unroll
    for (int g = 0; g < 4; ++g) {
      float4 bb = *reinterpret_cast<const float4*>(&sBd1[8 * g + 4 * hf]);
      cD[4*g+0] = bb.x; cD[4*g+1] = bb.y; cD[4*g+2] = bb.z; cD[4*g+3] = bb.w;
    }
    #pragma unroll
    for (int cc = 0; cc < 4; ++cc)
      cD = __builtin_amdgcn_mfma_f32_32x32x16_bf16(
             *reinterpret_cast<const bf16x8*>(&wd1TA[cc * 512 + L * 8]), xfhB[4 + cc], cD, 0, 0, 0);
    bf16x8 rB0, rB1;
    RELUPK(cD, rB0, rB1);
    f32x16 c2;
    #pragma unroll
    for (int i = 0; i < 4; ++i) c2[i] = sBd2[4 * hf + i];
    #pragma unroll
    for (int i = 4; i < 16; ++i) c2[i] = 0.0f;
    c2 = __builtin_amdgcn_mfma_f32_32x32x16_bf16(
           *reinterpret_cast<const bf16x8*>(&wd2TA[L * 8]), rB0, c2, 0, 0, 0);
    c2 = __builtin_amdgcn_mfma_f32_32x32x16_bf16(
           *reinterpret_cast<const bf16x8*>(&wd2TA[512 + L * 8]), rB1, c2, 0, 0, 0);
    float* op = out + ((b * FUT + s) * 32 + n5) * 6;
    if (hf == 0) {
      float p0 = predr[0] + c2[0];
      float p1 = predr[1] + c2[1];
      float p2 = predr[2] + c2[2];
      float p3 = predr[3] + c2[3];
      predr[0] = p0; predr[1] = p1; predr[2] = p2; predr[3] = p3;
      *reinterpret_cast<float2*>(op + 0) = make_float2(p0, p1);
      *reinterpret_cast<float2*>(op + 2) = make_float2(p2, p3);
    } else {
      float p4 = predr[0] + c2[0];
      float p5 = predr[1] + c2[1];
      predr[0] = p4; predr[1] = p5;
      *reinterpret_cast<float2*>(op + 4) = make_float2(p4, p5);
    }
    xBcur = BUILD_DECX();
  }
}

extern "C" void kernel_launch(void* const* d_in, const int* in_sizes, int n_in,
                              void* d_out, int out_size, void* d_ws, size_t ws_size,
                              hipStream_t stream) {
  (void)in_sizes; (void)n_in; (void)d_ws; (void)ws_size; (void)out_size;
  const float* xh   = (const float*)d_in[0];
  const float* adj  = (const float*)d_in[1];
  const float* Wenc = (const float*)d_in[2];
  const float* benc = (const float*)d_in[3];
  const float* Wg1  = (const float*)d_in[4];
  const float* bg1  = (const float*)d_in[5];
  const float* Wg2  = (const float*)d_in[6];
  const float* bg2  = (const float*)d_in[7];
  const float* Wih  = (const float*)d_in[8];
  const float* Whh  = (const float*)d_in[9];
  const float* bih  = (const float*)d_in[10];
  const float* bhh  = (const float*)d_in[11];
  const float* Wd1  = (const float*)d_in[12];
  const float* bd1  = (const float*)d_in[13];
  const float* Wd2  = (const float*)d_in[14];
  const float* bd2  = (const float*)d_in[15];
  float* out = (float*)d_out;
  stgnn_kernel<<<dim3(256), dim3(NT), 0, stream>>>(
      xh, adj, Wenc, benc, Wg1, bg1, Wg2, bg2,
      Wih, Whh, bih, bhh, Wd1, bd1, Wd2, bd2, out);
}